// Round 1
// baseline (1359.047 us; speedup 1.0000x reference)
//
#include <hip/hip_runtime.h>
#include <math.h>

#define N_NODES 100000
#define N_EDGES 3200000
#define F_IN    384
#define H1      128
#define H2      64

// ---------------- degree / normalization ----------------

__global__ void k_deg_init(int* __restrict__ deg) {
    int i = blockIdx.x * 256 + threadIdx.x;
    if (i < N_NODES) deg[i] = 1;               // self-loop
}

__global__ void k_deg_count(const int* __restrict__ dst, int* __restrict__ deg) {
    int e = blockIdx.x * 256 + threadIdx.x;
    if (e < N_EDGES) atomicAdd(&deg[dst[e]], 1);
}

__global__ void k_dis(const int* __restrict__ deg, float* __restrict__ dis) {
    int i = blockIdx.x * 256 + threadIdx.x;
    if (i < N_NODES) dis[i] = rsqrtf((float)deg[i]);   // deg >= 1 always
}

// ---------------- exclusive scan of (deg-1) -> CSR offsets ----------------
// 3-phase hierarchical scan. Each block covers 1024 elements (256 thr x 4).

__global__ void k_scan_a(const int* __restrict__ deg, int* __restrict__ bsum) {
    __shared__ int s[256];
    int b = blockIdx.x, t = threadIdx.x;
    int base = b * 1024 + t * 4;
    int l = 0;
    #pragma unroll
    for (int j = 0; j < 4; j++) {
        int idx = base + j;
        if (idx < N_NODES) l += deg[idx] - 1;
    }
    s[t] = l; __syncthreads();
    for (int off = 128; off > 0; off >>= 1) {
        if (t < off) s[t] += s[t + off];
        __syncthreads();
    }
    if (t == 0) bsum[b] = s[0];
}

__global__ void k_scan_b(const int* __restrict__ bsum, int* __restrict__ boff, int nb) {
    __shared__ int s[128];
    int t = threadIdx.x;
    int v = (t < nb) ? bsum[t] : 0;
    s[t] = v; __syncthreads();
    for (int off = 1; off < 128; off <<= 1) {
        int x = (t >= off) ? s[t - off] : 0;
        __syncthreads();
        s[t] += x;
        __syncthreads();
    }
    if (t < nb) boff[t] = s[t] - v;   // exclusive
}

__global__ void k_scan_c(const int* __restrict__ deg, const int* __restrict__ boff,
                         int* __restrict__ offsets, int* __restrict__ cursor) {
    __shared__ int s[256];
    int b = blockIdx.x, t = threadIdx.x;
    int base = b * 1024 + t * 4;
    int v[4]; int l = 0;
    #pragma unroll
    for (int j = 0; j < 4; j++) {
        int idx = base + j;
        v[j] = (idx < N_NODES) ? (deg[idx] - 1) : 0;
        l += v[j];
    }
    s[t] = l; __syncthreads();
    for (int off = 1; off < 256; off <<= 1) {
        int x = (t >= off) ? s[t - off] : 0;
        __syncthreads();
        s[t] += x;
        __syncthreads();
    }
    int run = boff[b] + (s[t] - l);   // block base + exclusive within block
    #pragma unroll
    for (int j = 0; j < 4; j++) {
        int idx = base + j;
        if (idx < N_NODES) { offsets[idx] = run; cursor[idx] = run; run += v[j]; }
    }
}

__global__ void k_fill(const int* __restrict__ src, const int* __restrict__ dst,
                       int* __restrict__ cursor, int* __restrict__ csr) {
    int e = blockIdx.x * 256 + threadIdx.x;
    if (e < N_EDGES) {
        int d = dst[e];
        int p = atomicAdd(&cursor[d], 1);
        csr[p] = src[e];
    }
}

// ---------------- GEMM1: h1 = x @ W1   [100000x384]@[384x128] ----------------
// 32x128 tile per block, BK=16, 4x4 micro-tile per thread.

__global__ __launch_bounds__(256) void k_gemm1(const float* __restrict__ x,
                                               const float* __restrict__ W1,
                                               float* __restrict__ h1) {
    __shared__ float xl[16][36];    // [k][row], +4 pad keeps 16B align
    __shared__ float wl[16][132];   // [k][col]
    int t = threadIdx.x;
    int m0 = blockIdx.x * 32;
    int tr = t >> 5, tc = t & 31;   // tr: 0..7 (row group), tc: 0..31 (col group)
    float acc[4][4] = {};
    for (int k0 = 0; k0 < F_IN; k0 += 16) {
        #pragma unroll
        for (int j = 0; j < 2; j++) {
            int idx = t + j * 256;
            int r = idx >> 4, k = idx & 15;
            xl[k][r] = x[(size_t)(m0 + r) * F_IN + k0 + k];
        }
        #pragma unroll
        for (int j = 0; j < 8; j++) {
            int idx = t + j * 256;
            int k = idx >> 7, c = idx & 127;
            wl[k][c] = W1[(size_t)(k0 + k) * H1 + c];
        }
        __syncthreads();
        #pragma unroll
        for (int kk = 0; kk < 16; kk++) {
            const float4 a = *(const float4*)&xl[kk][tr * 4];
            const float4 b = *(const float4*)&wl[kk][tc * 4];
            float av[4] = {a.x, a.y, a.z, a.w};
            float bv[4] = {b.x, b.y, b.z, b.w};
            #pragma unroll
            for (int i = 0; i < 4; i++)
                #pragma unroll
                for (int u = 0; u < 4; u++)
                    acc[i][u] += av[i] * bv[u];
        }
        __syncthreads();
    }
    #pragma unroll
    for (int i = 0; i < 4; i++) {
        float4 o = make_float4(acc[i][0], acc[i][1], acc[i][2], acc[i][3]);
        *(float4*)&h1[(size_t)(m0 + tr * 4 + i) * H1 + tc * 4] = o;
    }
}

// ---------------- agg1: hr = relu(segsum(h1[src]*norm) + b1) ----------------
// One wave per node; lane handles 2 of 128 features (float2).

__global__ __launch_bounds__(256) void k_agg1(const float* __restrict__ h1,
                                              const float* __restrict__ dis,
                                              const int* __restrict__ csr,
                                              const int* __restrict__ offsets,
                                              const int* __restrict__ deg,
                                              const float* __restrict__ b1,
                                              float* __restrict__ hr) {
    int w = (blockIdx.x * 256 + threadIdx.x) >> 6;
    if (w >= N_NODES) return;
    int lane = threadIdx.x & 63;
    int j = lane * 2;
    float di = dis[w];
    int start = offsets[w];
    int cnt = deg[w] - 1;
    float2 self = *(const float2*)&h1[(size_t)w * H1 + j];
    float ax = b1[j]     + self.x * di * di;
    float ay = b1[j + 1] + self.y * di * di;
    for (int k = 0; k < cnt; k++) {
        int s = csr[start + k];
        float wt = dis[s] * di;
        float2 hv = *(const float2*)&h1[(size_t)s * H1 + j];
        ax += hv.x * wt;
        ay += hv.y * wt;
    }
    float2 o = make_float2(fmaxf(ax, 0.f), fmaxf(ay, 0.f));
    *(float2*)&hr[(size_t)w * H1 + j] = o;
}

// ---------------- GEMM2: h2 = hr @ W2   [100000x128]@[128x64] ----------------

__global__ __launch_bounds__(256) void k_gemm2(const float* __restrict__ hr,
                                               const float* __restrict__ W2,
                                               float* __restrict__ h2) {
    __shared__ float hl[16][128];
    __shared__ float wl[128][64];
    int t = threadIdx.x;
    int m0 = blockIdx.x * 16;
    #pragma unroll
    for (int j = 0; j < 32; j++) {
        int idx = t + j * 256;
        wl[idx >> 6][idx & 63] = W2[idx];
    }
    #pragma unroll
    for (int j = 0; j < 2; j++) {
        int i4 = t + j * 256;
        int r = i4 >> 5, c4 = i4 & 31;
        *(float4*)&hl[r][c4 * 4] = *(const float4*)&hr[(size_t)(m0 + r) * H1 + c4 * 4];
    }
    __syncthreads();
    int c = t & 63, rg = t >> 6;
    float acc[4] = {};
    for (int k = 0; k < H1; k++) {
        float wv = wl[k][c];
        #pragma unroll
        for (int i = 0; i < 4; i++) acc[i] += hl[rg * 4 + i][k] * wv;
    }
    #pragma unroll
    for (int i = 0; i < 4; i++)
        h2[(size_t)(m0 + rg * 4 + i) * H2 + c] = acc[i];
}

// ---------------- agg2: out = segsum(h2[src]*norm) + b2 ----------------
// One wave per node; lane handles 1 of 64 features.

__global__ __launch_bounds__(256) void k_agg2(const float* __restrict__ h2,
                                              const float* __restrict__ dis,
                                              const int* __restrict__ csr,
                                              const int* __restrict__ offsets,
                                              const int* __restrict__ deg,
                                              const float* __restrict__ b2,
                                              float* __restrict__ out) {
    int w = (blockIdx.x * 256 + threadIdx.x) >> 6;
    if (w >= N_NODES) return;
    int lane = threadIdx.x & 63;
    float di = dis[w];
    int start = offsets[w];
    int cnt = deg[w] - 1;
    float acc = b2[lane] + h2[(size_t)w * H2 + lane] * di * di;
    for (int k = 0; k < cnt; k++) {
        int s = csr[start + k];
        float wt = dis[s] * di;
        acc += h2[(size_t)s * H2 + lane] * wt;
    }
    out[(size_t)w * H2 + lane] = acc;
}

// ---------------- launch ----------------

extern "C" void kernel_launch(void* const* d_in, const int* in_sizes, int n_in,
                              void* d_out, int out_size, void* d_ws, size_t ws_size,
                              hipStream_t stream) {
    const float* x  = (const float*)d_in[0];
    const float* W1 = (const float*)d_in[1];
    const float* b1 = (const float*)d_in[2];
    const float* W2 = (const float*)d_in[3];
    const float* b2 = (const float*)d_in[4];
    const int*   ei = (const int*)d_in[5];
    const int* src = ei;
    const int* dst = ei + N_EDGES;
    float* out = (float*)d_out;

    char* ws = (char*)d_ws;
    int*   deg     = (int*)ws;  ws += (size_t)N_NODES * 4;
    float* dis     = (float*)ws; ws += (size_t)N_NODES * 4;
    int*   bsum    = (int*)ws;  ws += 128 * 4;
    int*   boff    = (int*)ws;  ws += 128 * 4;
    int*   offsets = (int*)ws;  ws += (size_t)N_NODES * 4;
    int*   cursor  = (int*)ws;  ws += (size_t)N_NODES * 4;
    int*   csr     = (int*)ws;  ws += (size_t)N_EDGES * 4;
    float* h1      = (float*)ws; ws += (size_t)N_NODES * H1 * 4;
    float* hr      = (float*)ws; ws += (size_t)N_NODES * H1 * 4;
    float* h2      = h1;   // h1 dead after agg1; alias

    const int NB_N = (N_NODES + 255) / 256;          // 391
    const int NB_E = (N_EDGES + 255) / 256;          // 12500
    const int NB_S = (N_NODES + 1023) / 1024;        // 98

    k_deg_init<<<NB_N, 256, 0, stream>>>(deg);
    k_deg_count<<<NB_E, 256, 0, stream>>>(dst, deg);
    k_dis<<<NB_N, 256, 0, stream>>>(deg, dis);
    k_scan_a<<<NB_S, 256, 0, stream>>>(deg, bsum);
    k_scan_b<<<1, 128, 0, stream>>>(bsum, boff, NB_S);
    k_scan_c<<<NB_S, 256, 0, stream>>>(deg, boff, offsets, cursor);
    k_fill<<<NB_E, 256, 0, stream>>>(src, dst, cursor, csr);

    k_gemm1<<<N_NODES / 32, 256, 0, stream>>>(x, W1, h1);
    k_agg1<<<(N_NODES + 3) / 4, 256, 0, stream>>>(h1, dis, csr, offsets, deg, b1, hr);
    k_gemm2<<<N_NODES / 16, 256, 0, stream>>>(hr, W2, h2);
    k_agg2<<<(N_NODES + 3) / 4, 256, 0, stream>>>(h2, dis, csr, offsets, deg, b2, out);
}

// Round 2
// 1097.191 us; speedup vs baseline: 1.2387x; 1.2387x over previous
//
#include <hip/hip_runtime.h>
#include <math.h>

#define N_NODES 100000
#define N_EDGES 3200000
#define F_IN    384
#define H1      128
#define H2      64

// ---------------- degree / normalization ----------------

__global__ void k_deg_init(int* __restrict__ deg) {
    int i = blockIdx.x * 256 + threadIdx.x;
    if (i < N_NODES) deg[i] = 1;               // self-loop
}

__global__ void k_deg_count(const int* __restrict__ dst, int* __restrict__ deg) {
    int e = blockIdx.x * 256 + threadIdx.x;
    if (e < N_EDGES) atomicAdd(&deg[dst[e]], 1);
}

__global__ void k_dis(const int* __restrict__ deg, float* __restrict__ dis) {
    int i = blockIdx.x * 256 + threadIdx.x;
    if (i < N_NODES) dis[i] = rsqrtf((float)deg[i]);   // deg >= 1 always
}

// ---------------- exclusive scan of (deg-1) -> CSR offsets ----------------

__global__ void k_scan_a(const int* __restrict__ deg, int* __restrict__ bsum) {
    __shared__ int s[256];
    int b = blockIdx.x, t = threadIdx.x;
    int base = b * 1024 + t * 4;
    int l = 0;
    #pragma unroll
    for (int j = 0; j < 4; j++) {
        int idx = base + j;
        if (idx < N_NODES) l += deg[idx] - 1;
    }
    s[t] = l; __syncthreads();
    for (int off = 128; off > 0; off >>= 1) {
        if (t < off) s[t] += s[t + off];
        __syncthreads();
    }
    if (t == 0) bsum[b] = s[0];
}

__global__ void k_scan_b(const int* __restrict__ bsum, int* __restrict__ boff, int nb) {
    __shared__ int s[128];
    int t = threadIdx.x;
    int v = (t < nb) ? bsum[t] : 0;
    s[t] = v; __syncthreads();
    for (int off = 1; off < 128; off <<= 1) {
        int x = (t >= off) ? s[t - off] : 0;
        __syncthreads();
        s[t] += x;
        __syncthreads();
    }
    if (t < nb) boff[t] = s[t] - v;   // exclusive
}

__global__ void k_scan_c(const int* __restrict__ deg, const int* __restrict__ boff,
                         int* __restrict__ offsets, int* __restrict__ cursor) {
    __shared__ int s[256];
    int b = blockIdx.x, t = threadIdx.x;
    int base = b * 1024 + t * 4;
    int v[4]; int l = 0;
    #pragma unroll
    for (int j = 0; j < 4; j++) {
        int idx = base + j;
        v[j] = (idx < N_NODES) ? (deg[idx] - 1) : 0;
        l += v[j];
    }
    s[t] = l; __syncthreads();
    for (int off = 1; off < 256; off <<= 1) {
        int x = (t >= off) ? s[t - off] : 0;
        __syncthreads();
        s[t] += x;
        __syncthreads();
    }
    int run = boff[b] + (s[t] - l);
    #pragma unroll
    for (int j = 0; j < 4; j++) {
        int idx = base + j;
        if (idx < N_NODES) { offsets[idx] = run; cursor[idx] = run; run += v[j]; }
    }
}

__global__ void k_fill(const int* __restrict__ src, const int* __restrict__ dst,
                       int* __restrict__ cursor, int* __restrict__ csr) {
    int e = blockIdx.x * 256 + threadIdx.x;
    if (e < N_EDGES) {
        int d = dst[e];
        int p = atomicAdd(&cursor[d], 1);
        csr[p] = src[e];
    }
}

// ---------------- GEMM1: h1 = x @ W1   [100000x384]@[384x128] ----------------
// 64x128 tile per block, BK=16, 8x4 micro-tile per thread.

__global__ __launch_bounds__(256) void k_gemm1(const float* __restrict__ x,
                                               const float* __restrict__ W1,
                                               float* __restrict__ h1) {
    __shared__ float xl[16][72];    // [k][row 0..63], padded stride 72
    __shared__ float wl[16][128];   // [k][col]
    int t = threadIdx.x;
    int m0 = blockIdx.x * 64;
    int tr = t >> 5, tc = t & 31;   // tr: 0..7 (8-row group), tc: 0..31 (4-col group)
    float acc[8][4] = {};
    for (int k0 = 0; k0 < F_IN; k0 += 16) {
        {   // stage x: 64 rows x 16 k = 1024 floats, float4 per thread along k
            int r = t >> 2, kq = (t & 3) * 4;
            int rr = m0 + r; if (rr >= N_NODES) rr = N_NODES - 1;
            float4 a = *(const float4*)&x[(size_t)rr * F_IN + k0 + kq];
            xl[kq][r] = a.x; xl[kq + 1][r] = a.y; xl[kq + 2][r] = a.z; xl[kq + 3][r] = a.w;
        }
        #pragma unroll
        for (int jj = 0; jj < 2; jj++) {   // stage W: 16x128 floats, 2 float4/thread
            int idx = t + jj * 256;
            int k = idx >> 5, c4 = idx & 31;
            *(float4*)&wl[k][c4 * 4] = *(const float4*)&W1[(size_t)(k0 + k) * H1 + c4 * 4];
        }
        __syncthreads();
        #pragma unroll
        for (int kk = 0; kk < 16; kk++) {
            float4 a0 = *(const float4*)&xl[kk][tr * 8];
            float4 a1 = *(const float4*)&xl[kk][tr * 8 + 4];
            float4 b  = *(const float4*)&wl[kk][tc * 4];
            float av[8] = {a0.x, a0.y, a0.z, a0.w, a1.x, a1.y, a1.z, a1.w};
            float bv[4] = {b.x, b.y, b.z, b.w};
            #pragma unroll
            for (int i = 0; i < 8; i++)
                #pragma unroll
                for (int u = 0; u < 4; u++)
                    acc[i][u] += av[i] * bv[u];
        }
        __syncthreads();
    }
    #pragma unroll
    for (int i = 0; i < 8; i++) {
        int row = m0 + tr * 8 + i;
        if (row < N_NODES) {
            float4 o = make_float4(acc[i][0], acc[i][1], acc[i][2], acc[i][3]);
            *(float4*)&h1[(size_t)row * H1 + tc * 4] = o;
        }
    }
}

// ---------------- agg1: hr = relu(di * segsum(dis[s]*h1[s]) + b1) ----------------
// One wave per node; lane handles 2 of 128 features. 8x unrolled gather for MLP.

__global__ __launch_bounds__(256) void k_agg1(const float* __restrict__ h1,
                                              const float* __restrict__ dis,
                                              const int* __restrict__ csr,
                                              const int* __restrict__ offsets,
                                              const int* __restrict__ deg,
                                              const float* __restrict__ b1,
                                              float* __restrict__ hr) {
    int w = (blockIdx.x * 256 + threadIdx.x) >> 6;
    if (w >= N_NODES) return;
    int lane = threadIdx.x & 63;
    int j = lane * 2;
    const float2* __restrict__ h = (const float2*)h1;
    float di = dis[w];
    int start = offsets[w];
    int cnt = deg[w] - 1;
    float2 self = h[(size_t)w * 64 + lane];
    float sx = di * self.x;
    float sy = di * self.y;
    for (int k = 0; k < cnt; k += 8) {
        int   s[8]; float wd[8]; float2 v[8];
        #pragma unroll
        for (int u = 0; u < 8; u++) {
            int kk = k + u;
            s[u] = csr[start + (kk < cnt ? kk : cnt - 1)];
        }
        #pragma unroll
        for (int u = 0; u < 8; u++) {
            wd[u] = (k + u < cnt) ? dis[s[u]] : 0.f;
            v[u]  = h[(size_t)s[u] * 64 + lane];
        }
        #pragma unroll
        for (int u = 0; u < 8; u++) {
            sx += v[u].x * wd[u];
            sy += v[u].y * wd[u];
        }
    }
    float2 o = make_float2(fmaxf(b1[j]     + di * sx, 0.f),
                           fmaxf(b1[j + 1] + di * sy, 0.f));
    *(float2*)&hr[(size_t)w * H1 + j] = o;
}

// ---------------- GEMM2: h2 = hr @ W2   [100000x128]@[128x64] ----------------

__global__ __launch_bounds__(256) void k_gemm2(const float* __restrict__ hr,
                                               const float* __restrict__ W2,
                                               float* __restrict__ h2) {
    __shared__ float hl[16][128];
    __shared__ float wl[128][64];
    int t = threadIdx.x;
    int m0 = blockIdx.x * 16;
    #pragma unroll
    for (int j = 0; j < 32; j++) {
        int idx = t + j * 256;
        wl[idx >> 6][idx & 63] = W2[idx];
    }
    #pragma unroll
    for (int j = 0; j < 2; j++) {
        int i4 = t + j * 256;
        int r = i4 >> 5, c4 = i4 & 31;
        *(float4*)&hl[r][c4 * 4] = *(const float4*)&hr[(size_t)(m0 + r) * H1 + c4 * 4];
    }
    __syncthreads();
    int c = t & 63, rg = t >> 6;
    float acc[4] = {};
    for (int k = 0; k < H1; k++) {
        float wv = wl[k][c];
        #pragma unroll
        for (int i = 0; i < 4; i++) acc[i] += hl[rg * 4 + i][k] * wv;
    }
    #pragma unroll
    for (int i = 0; i < 4; i++)
        h2[(size_t)(m0 + rg * 4 + i) * H2 + c] = acc[i];
}

// ---------------- agg2: out = di * segsum(dis[s]*h2[s]) + b2 ----------------
// One wave per node; lane handles 1 of 64 features. 8x unrolled gather.

__global__ __launch_bounds__(256) void k_agg2(const float* __restrict__ h2,
                                              const float* __restrict__ dis,
                                              const int* __restrict__ csr,
                                              const int* __restrict__ offsets,
                                              const int* __restrict__ deg,
                                              const float* __restrict__ b2,
                                              float* __restrict__ out) {
    int w = (blockIdx.x * 256 + threadIdx.x) >> 6;
    if (w >= N_NODES) return;
    int lane = threadIdx.x & 63;
    float di = dis[w];
    int start = offsets[w];
    int cnt = deg[w] - 1;
    float acc = di * h2[(size_t)w * H2 + lane];
    for (int k = 0; k < cnt; k += 8) {
        int s[8]; float wd[8]; float v[8];
        #pragma unroll
        for (int u = 0; u < 8; u++) {
            int kk = k + u;
            s[u] = csr[start + (kk < cnt ? kk : cnt - 1)];
        }
        #pragma unroll
        for (int u = 0; u < 8; u++) {
            wd[u] = (k + u < cnt) ? dis[s[u]] : 0.f;
            v[u]  = h2[(size_t)s[u] * H2 + lane];
        }
        #pragma unroll
        for (int u = 0; u < 8; u++) acc += v[u] * wd[u];
    }
    out[(size_t)w * H2 + lane] = b2[lane] + di * acc;
}

// ---------------- launch ----------------

extern "C" void kernel_launch(void* const* d_in, const int* in_sizes, int n_in,
                              void* d_out, int out_size, void* d_ws, size_t ws_size,
                              hipStream_t stream) {
    const float* x  = (const float*)d_in[0];
    const float* W1 = (const float*)d_in[1];
    const float* b1 = (const float*)d_in[2];
    const float* W2 = (const float*)d_in[3];
    const float* b2 = (const float*)d_in[4];
    const int*   ei = (const int*)d_in[5];
    const int* src = ei;
    const int* dst = ei + N_EDGES;
    float* out = (float*)d_out;

    char* ws = (char*)d_ws;
    int*   deg     = (int*)ws;  ws += (size_t)N_NODES * 4;
    float* dis     = (float*)ws; ws += (size_t)N_NODES * 4;
    int*   bsum    = (int*)ws;  ws += 128 * 4;
    int*   boff    = (int*)ws;  ws += 128 * 4;
    int*   offsets = (int*)ws;  ws += (size_t)N_NODES * 4;
    int*   cursor  = (int*)ws;  ws += (size_t)N_NODES * 4;
    int*   csr     = (int*)ws;  ws += (size_t)N_EDGES * 4;
    float* h1      = (float*)ws; ws += (size_t)N_NODES * H1 * 4;
    float* hr      = (float*)ws; ws += (size_t)N_NODES * H1 * 4;
    float* h2      = h1;   // h1 dead after agg1; alias

    const int NB_N = (N_NODES + 255) / 256;
    const int NB_E = (N_EDGES + 255) / 256;
    const int NB_S = (N_NODES + 1023) / 1024;

    k_deg_init<<<NB_N, 256, 0, stream>>>(deg);
    k_deg_count<<<NB_E, 256, 0, stream>>>(dst, deg);
    k_dis<<<NB_N, 256, 0, stream>>>(deg, dis);
    k_scan_a<<<NB_S, 256, 0, stream>>>(deg, bsum);
    k_scan_b<<<1, 128, 0, stream>>>(bsum, boff, NB_S);
    k_scan_c<<<NB_S, 256, 0, stream>>>(deg, boff, offsets, cursor);
    k_fill<<<NB_E, 256, 0, stream>>>(src, dst, cursor, csr);

    k_gemm1<<<(N_NODES + 63) / 64, 256, 0, stream>>>(x, W1, h1);
    k_agg1<<<(N_NODES + 3) / 4, 256, 0, stream>>>(h1, dis, csr, offsets, deg, b1, hr);
    k_gemm2<<<N_NODES / 16, 256, 0, stream>>>(hr, W2, h2);
    k_agg2<<<(N_NODES + 3) / 4, 256, 0, stream>>>(h2, dis, csr, offsets, deg, b2, out);
}

// Round 4
// 841.433 us; speedup vs baseline: 1.6152x; 1.3040x over previous
//
#include <hip/hip_runtime.h>
#include <math.h>

#define N_NODES 100000
#define N_EDGES 3200000
#define F_IN    384
#define H1      128
#define H2      64

#define NBKT    782          // ceil(N_NODES / 128)
#define HIST_W  800          // padded bucket-row width
#define NB_BIN  256          // binning blocks
#define EPB     (N_EDGES / NB_BIN)   // 12500 edges per bin block

// ---------------- phase A1: per-block bucket histograms ----------------

__global__ __launch_bounds__(256) void k_hist(const int* __restrict__ dst,
                                              int* __restrict__ hist) {
    __shared__ int h[HIST_W];
    int b = blockIdx.x, t = threadIdx.x;
    for (int i = t; i < HIST_W; i += 256) h[i] = 0;
    __syncthreads();
    int e0 = b * EPB, e1 = e0 + EPB;
    for (int e = e0 + t; e < e1; e += 256)
        atomicAdd(&h[dst[e] >> 7], 1);
    __syncthreads();
    for (int i = t; i < HIST_W; i += 256) hist[b * HIST_W + i] = h[i];
}

// ---------------- phase A2: bucket bases + per-(block,bucket) offsets ----------------

__global__ __launch_bounds__(1024) void k_scan_off(int* __restrict__ hist,
                                                   int* __restrict__ bucketBase) {
    __shared__ int s[1024];
    int t = threadIdx.x;
    int run = 0;
    if (t < HIST_W) {
        #pragma unroll 8
        for (int b = 0; b < NB_BIN; b++) {
            int v = hist[b * HIST_W + t];
            hist[b * HIST_W + t] = run;   // prefix over blocks, within bucket
            run += v;
        }
    }
    int tot = (t < NBKT) ? run : 0;
    s[t] = tot; __syncthreads();
    for (int off = 1; off < 1024; off <<= 1) {
        int x = (t >= off) ? s[t - off] : 0;
        __syncthreads();
        s[t] += x;
        __syncthreads();
    }
    if (t <= NBKT) bucketBase[t] = s[t] - tot;   // exclusive over buckets
}

// ---------------- phase A3: scatter packed edges into bucket order ----------------

__global__ __launch_bounds__(256) void k_bin(const int* __restrict__ src,
                                             const int* __restrict__ dst,
                                             const int* __restrict__ hist,
                                             const int* __restrict__ bucketBase,
                                             int* __restrict__ binned) {
    __shared__ int lcur[HIST_W];
    int b = blockIdx.x, t = threadIdx.x;
    for (int i = t; i < HIST_W; i += 256)
        lcur[i] = ((i < NBKT) ? bucketBase[i] : 0) + hist[b * HIST_W + i];
    __syncthreads();
    int e0 = b * EPB, e1 = e0 + EPB;
    for (int e = e0 + t; e < e1; e += 256) {
        int d = dst[e];
        int p = atomicAdd(&lcur[d >> 7], 1);
        binned[p] = ((d & 127) << 17) | src[e];   // src < 2^17
    }
}

// ---------------- phase B: per-bucket deg/dis/offsets/csr (all in LDS) ----------------

__global__ __launch_bounds__(256) void k_build(const int* __restrict__ binned,
                                               const int* __restrict__ bucketBase,
                                               int* __restrict__ csr,
                                               int* __restrict__ offsets,
                                               int* __restrict__ ecnt,
                                               float* __restrict__ dis) {
    __shared__ int ldeg[128], spre[128], lcur[128];
    int bkt = blockIdx.x, t = threadIdx.x;
    int e0 = bucketBase[bkt], e1 = bucketBase[bkt + 1];
    if (t < 128) ldeg[t] = 0;
    __syncthreads();
    for (int e = e0 + t; e < e1; e += 256)
        atomicAdd(&ldeg[binned[e] >> 17], 1);
    __syncthreads();
    int v = (t < 128) ? ldeg[t] : 0;
    if (t < 128) spre[t] = v;
    __syncthreads();
    for (int off = 1; off < 128; off <<= 1) {
        int x = (t < 128 && t >= off) ? spre[t - off] : 0;
        __syncthreads();
        if (t < 128) spre[t] += x;
        __syncthreads();
    }
    if (t < 128) {
        int node = bkt * 128 + t;
        if (node < N_NODES) {
            int base = e0 + spre[t] - v;   // exclusive prefix within bucket
            offsets[node] = base;
            ecnt[node]    = v;             // neighbors excluding self-loop
            dis[node]     = rsqrtf((float)(v + 1));
            lcur[t]       = base;
        }
    }
    __syncthreads();
    for (int e = e0 + t; e < e1; e += 256) {
        int p = binned[e];
        int pos = atomicAdd(&lcur[p >> 17], 1);
        csr[pos] = p & 0x1FFFF;
    }
}

// ---------------- GEMM1: h1 = x @ W1   [100000x384]@[384x128] ----------------

__global__ __launch_bounds__(256) void k_gemm1(const float* __restrict__ x,
                                               const float* __restrict__ W1,
                                               float* __restrict__ h1) {
    __shared__ float xl[16][72];
    __shared__ float wl[16][128];
    int t = threadIdx.x;
    int m0 = blockIdx.x * 64;
    int tr = t >> 5, tc = t & 31;
    float acc[8][4] = {};
    for (int k0 = 0; k0 < F_IN; k0 += 16) {
        {
            int r = t >> 2, kq = (t & 3) * 4;
            int rr = m0 + r; if (rr >= N_NODES) rr = N_NODES - 1;
            float4 a = *(const float4*)&x[(size_t)rr * F_IN + k0 + kq];
            xl[kq][r] = a.x; xl[kq + 1][r] = a.y; xl[kq + 2][r] = a.z; xl[kq + 3][r] = a.w;
        }
        #pragma unroll
        for (int jj = 0; jj < 2; jj++) {
            int idx = t + jj * 256;
            int k = idx >> 5, c4 = idx & 31;
            *(float4*)&wl[k][c4 * 4] = *(const float4*)&W1[(size_t)(k0 + k) * H1 + c4 * 4];
        }
        __syncthreads();
        #pragma unroll
        for (int kk = 0; kk < 16; kk++) {
            float4 a0 = *(const float4*)&xl[kk][tr * 8];
            float4 a1 = *(const float4*)&xl[kk][tr * 8 + 4];
            float4 b  = *(const float4*)&wl[kk][tc * 4];
            float av[8] = {a0.x, a0.y, a0.z, a0.w, a1.x, a1.y, a1.z, a1.w};
            float bv[4] = {b.x, b.y, b.z, b.w};
            #pragma unroll
            for (int i = 0; i < 8; i++)
                #pragma unroll
                for (int u = 0; u < 4; u++)
                    acc[i][u] += av[i] * bv[u];
        }
        __syncthreads();
    }
    #pragma unroll
    for (int i = 0; i < 8; i++) {
        int row = m0 + tr * 8 + i;
        if (row < N_NODES) {
            float4 o = make_float4(acc[i][0], acc[i][1], acc[i][2], acc[i][3]);
            *(float4*)&h1[(size_t)row * H1 + tc * 4] = o;
        }
    }
}

// ---------------- agg1: hr = relu(di * segsum(dis[s]*h1[s]) + b1) ----------------

__global__ __launch_bounds__(256) void k_agg1(const float* __restrict__ h1,
                                              const float* __restrict__ dis,
                                              const int* __restrict__ csr,
                                              const int* __restrict__ offsets,
                                              const int* __restrict__ ecnt,
                                              const float* __restrict__ b1,
                                              float* __restrict__ hr) {
    int w = (blockIdx.x * 256 + threadIdx.x) >> 6;
    if (w >= N_NODES) return;
    int lane = threadIdx.x & 63;
    int j = lane * 2;
    const float2* __restrict__ h = (const float2*)h1;
    float di = dis[w];
    int start = offsets[w];
    int cnt = ecnt[w];
    float2 self = h[(size_t)w * 64 + lane];
    float sx = di * self.x;
    float sy = di * self.y;
    for (int k = 0; k < cnt; k += 8) {
        int   s[8]; float wd[8]; float2 v[8];
        #pragma unroll
        for (int u = 0; u < 8; u++) {
            int kk = k + u;
            s[u] = csr[start + (kk < cnt ? kk : cnt - 1)];
        }
        #pragma unroll
        for (int u = 0; u < 8; u++) {
            wd[u] = (k + u < cnt) ? dis[s[u]] : 0.f;
            v[u]  = h[(size_t)s[u] * 64 + lane];
        }
        #pragma unroll
        for (int u = 0; u < 8; u++) {
            sx += v[u].x * wd[u];
            sy += v[u].y * wd[u];
        }
    }
    float2 o = make_float2(fmaxf(b1[j]     + di * sx, 0.f),
                           fmaxf(b1[j + 1] + di * sy, 0.f));
    *(float2*)&hr[(size_t)w * H1 + j] = o;
}

// ---------------- GEMM2: h2 = hr @ W2   [100000x128]@[128x64] ----------------
// 32-row tile, 8 rows per thread group.

__global__ __launch_bounds__(256) void k_gemm2(const float* __restrict__ hr,
                                               const float* __restrict__ W2,
                                               float* __restrict__ h2) {
    __shared__ float hl[32][128];
    __shared__ float wl[128][64];
    int t = threadIdx.x;
    int m0 = blockIdx.x * 32;
    #pragma unroll
    for (int j = 0; j < 8; j++) {
        int i4 = t + j * 256;
        int r = i4 >> 4, c4 = i4 & 15;
        *(float4*)&wl[r][c4 * 4] = *(const float4*)&W2[(size_t)r * H2 + c4 * 4];
    }
    #pragma unroll
    for (int j = 0; j < 4; j++) {
        int i4 = t + j * 256;
        int r = i4 >> 5, c4 = i4 & 31;
        *(float4*)&hl[r][c4 * 4] = *(const float4*)&hr[(size_t)(m0 + r) * H1 + c4 * 4];
    }
    __syncthreads();
    int c = t & 63, rg = t >> 6;
    float acc[8] = {};
    for (int k = 0; k < H1; k++) {
        float wv = wl[k][c];
        #pragma unroll
        for (int i = 0; i < 8; i++) acc[i] += hl[rg * 8 + i][k] * wv;   // hl broadcast
    }
    #pragma unroll
    for (int i = 0; i < 8; i++)
        h2[(size_t)(m0 + rg * 8 + i) * H2 + c] = acc[i];
}

// ---------------- agg2: out = di * segsum(dis[s]*h2[s]) + b2 ----------------

__global__ __launch_bounds__(256) void k_agg2(const float* __restrict__ h2,
                                              const float* __restrict__ dis,
                                              const int* __restrict__ csr,
                                              const int* __restrict__ offsets,
                                              const int* __restrict__ ecnt,
                                              const float* __restrict__ b2,
                                              float* __restrict__ out) {
    int w = (blockIdx.x * 256 + threadIdx.x) >> 6;
    if (w >= N_NODES) return;
    int lane = threadIdx.x & 63;
    float di = dis[w];
    int start = offsets[w];
    int cnt = ecnt[w];
    float acc = di * h2[(size_t)w * H2 + lane];
    for (int k = 0; k < cnt; k += 8) {
        int s[8]; float wd[8]; float v[8];
        #pragma unroll
        for (int u = 0; u < 8; u++) {
            int kk = k + u;
            s[u] = csr[start + (kk < cnt ? kk : cnt - 1)];
        }
        #pragma unroll
        for (int u = 0; u < 8; u++) {
            wd[u] = (k + u < cnt) ? dis[s[u]] : 0.f;
            v[u]  = h2[(size_t)s[u] * H2 + lane];
        }
        #pragma unroll
        for (int u = 0; u < 8; u++) acc += v[u] * wd[u];
    }
    out[(size_t)w * H2 + lane] = b2[lane] + di * acc;
}

// ---------------- launch ----------------

extern "C" void kernel_launch(void* const* d_in, const int* in_sizes, int n_in,
                              void* d_out, int out_size, void* d_ws, size_t ws_size,
                              hipStream_t stream) {
    const float* x  = (const float*)d_in[0];
    const float* W1 = (const float*)d_in[1];
    const float* b1 = (const float*)d_in[2];
    const float* W2 = (const float*)d_in[3];
    const float* b2 = (const float*)d_in[4];
    const int*   ei = (const int*)d_in[5];
    const int* src = ei;
    const int* dst = ei + N_EDGES;
    float* out = (float*)d_out;

    char* ws = (char*)d_ws;
    float* dis        = (float*)ws; ws += (size_t)N_NODES * 4;
    int*   offsets    = (int*)ws;   ws += (size_t)N_NODES * 4;
    int*   ecnt       = (int*)ws;   ws += (size_t)N_NODES * 4;
    int*   bucketBase = (int*)ws;   ws += 1024 * 4;
    int*   hist       = (int*)ws;   ws += (size_t)NB_BIN * HIST_W * 4;
    int*   csr        = (int*)ws;   ws += (size_t)N_EDGES * 4;
    float* h1         = (float*)ws; ws += (size_t)N_NODES * H1 * 4;
    float* hr         = (float*)ws; ws += (size_t)N_NODES * H1 * 4;
    int*   binned     = (int*)h1;   // dead after k_build; gemm1 overwrites
    float* h2         = h1;         // h1 dead after agg1

    k_hist    <<<NB_BIN, 256, 0, stream>>>(dst, hist);
    k_scan_off<<<1, 1024, 0, stream>>>(hist, bucketBase);
    k_bin     <<<NB_BIN, 256, 0, stream>>>(src, dst, hist, bucketBase, binned);
    k_build   <<<NBKT, 256, 0, stream>>>(binned, bucketBase, csr, offsets, ecnt, dis);

    k_gemm1<<<(N_NODES + 63) / 64, 256, 0, stream>>>(x, W1, h1);
    k_agg1<<<(N_NODES + 3) / 4, 256, 0, stream>>>(h1, dis, csr, offsets, ecnt, b1, hr);
    k_gemm2<<<N_NODES / 32, 256, 0, stream>>>(hr, W2, h2);
    k_agg2<<<(N_NODES + 3) / 4, 256, 0, stream>>>(h2, dis, csr, offsets, ecnt, b2, out);
}

// Round 5
// 689.368 us; speedup vs baseline: 1.9714x; 1.2206x over previous
//
#include <hip/hip_runtime.h>
#include <hip/hip_fp16.h>
#include <math.h>

#define N_NODES 100000
#define N_EDGES 3200000
#define F_IN    384
#define H1      128
#define H2      64

#define NBKT    782          // ceil(N_NODES / 128)
#define HIST_W  800          // padded bucket-row width
#define NB_BIN  256          // binning blocks
#define EPB     (N_EDGES / NB_BIN)   // 12500 edges per bin block

// ---------------- phase A1: per-block bucket histograms ----------------

__global__ __launch_bounds__(256) void k_hist(const int* __restrict__ dst,
                                              int* __restrict__ hist) {
    __shared__ int h[HIST_W];
    int b = blockIdx.x, t = threadIdx.x;
    for (int i = t; i < HIST_W; i += 256) h[i] = 0;
    __syncthreads();
    int e0 = b * EPB, e1 = e0 + EPB;
    for (int e = e0 + t; e < e1; e += 256)
        atomicAdd(&h[dst[e] >> 7], 1);
    __syncthreads();
    for (int i = t; i < HIST_W; i += 256) hist[b * HIST_W + i] = h[i];
}

// ---------------- phase A2: bucket bases + per-(block,bucket) offsets ----------------

__global__ __launch_bounds__(1024) void k_scan_off(int* __restrict__ hist,
                                                   int* __restrict__ bucketBase) {
    __shared__ int s[1024];
    int t = threadIdx.x;
    int run = 0;
    if (t < HIST_W) {
        #pragma unroll 8
        for (int b = 0; b < NB_BIN; b++) {
            int v = hist[b * HIST_W + t];
            hist[b * HIST_W + t] = run;   // prefix over blocks, within bucket
            run += v;
        }
    }
    int tot = (t < NBKT) ? run : 0;
    s[t] = tot; __syncthreads();
    for (int off = 1; off < 1024; off <<= 1) {
        int x = (t >= off) ? s[t - off] : 0;
        __syncthreads();
        s[t] += x;
        __syncthreads();
    }
    if (t <= NBKT) bucketBase[t] = s[t] - tot;   // exclusive over buckets
}

// ---------------- phase A3: scatter packed edges into bucket order ----------------

__global__ __launch_bounds__(256) void k_bin(const int* __restrict__ src,
                                             const int* __restrict__ dst,
                                             const int* __restrict__ hist,
                                             const int* __restrict__ bucketBase,
                                             int* __restrict__ binned) {
    __shared__ int lcur[HIST_W];
    int b = blockIdx.x, t = threadIdx.x;
    for (int i = t; i < HIST_W; i += 256)
        lcur[i] = ((i < NBKT) ? bucketBase[i] : 0) + hist[b * HIST_W + i];
    __syncthreads();
    int e0 = b * EPB, e1 = e0 + EPB;
    for (int e = e0 + t; e < e1; e += 256) {
        int d = dst[e];
        int p = atomicAdd(&lcur[d >> 7], 1);
        binned[p] = ((d & 127) << 17) | src[e];   // src < 2^17
    }
}

// ---------------- phase B: per-bucket deg/dis/offsets/csr (all in LDS) ----------------

__global__ __launch_bounds__(256) void k_build(const int* __restrict__ binned,
                                               const int* __restrict__ bucketBase,
                                               int* __restrict__ csr,
                                               int* __restrict__ offsets,
                                               int* __restrict__ ecnt,
                                               float* __restrict__ dis) {
    __shared__ int ldeg[128], spre[128], lcur[128];
    int bkt = blockIdx.x, t = threadIdx.x;
    int e0 = bucketBase[bkt], e1 = bucketBase[bkt + 1];
    if (t < 128) ldeg[t] = 0;
    __syncthreads();
    for (int e = e0 + t; e < e1; e += 256)
        atomicAdd(&ldeg[binned[e] >> 17], 1);
    __syncthreads();
    int v = (t < 128) ? ldeg[t] : 0;
    if (t < 128) spre[t] = v;
    __syncthreads();
    for (int off = 1; off < 128; off <<= 1) {
        int x = (t < 128 && t >= off) ? spre[t - off] : 0;
        __syncthreads();
        if (t < 128) spre[t] += x;
        __syncthreads();
    }
    if (t < 128) {
        int node = bkt * 128 + t;
        if (node < N_NODES) {
            int base = e0 + spre[t] - v;   // exclusive prefix within bucket
            offsets[node] = base;
            ecnt[node]    = v;             // neighbors excluding self-loop
            dis[node]     = rsqrtf((float)(v + 1));
            lcur[t]       = base;
        }
    }
    __syncthreads();
    for (int e = e0 + t; e < e1; e += 256) {
        int p = binned[e];
        int pos = atomicAdd(&lcur[p >> 17], 1);
        csr[pos] = p & 0x1FFFF;
    }
}

// ---------------- GEMM1: hs1 = fp16(dis * (x @ W1)) ----------------

__global__ __launch_bounds__(256) void k_gemm1(const float* __restrict__ x,
                                               const float* __restrict__ W1,
                                               const float* __restrict__ dis,
                                               __half* __restrict__ hs1) {
    __shared__ float xl[16][72];
    __shared__ float wl[16][128];
    int t = threadIdx.x;
    int m0 = blockIdx.x * 64;
    int tr = t >> 5, tc = t & 31;
    float acc[8][4] = {};
    for (int k0 = 0; k0 < F_IN; k0 += 16) {
        {
            int r = t >> 2, kq = (t & 3) * 4;
            int rr = m0 + r; if (rr >= N_NODES) rr = N_NODES - 1;
            float4 a = *(const float4*)&x[(size_t)rr * F_IN + k0 + kq];
            xl[kq][r] = a.x; xl[kq + 1][r] = a.y; xl[kq + 2][r] = a.z; xl[kq + 3][r] = a.w;
        }
        #pragma unroll
        for (int jj = 0; jj < 2; jj++) {
            int idx = t + jj * 256;
            int k = idx >> 5, c4 = idx & 31;
            *(float4*)&wl[k][c4 * 4] = *(const float4*)&W1[(size_t)(k0 + k) * H1 + c4 * 4];
        }
        __syncthreads();
        #pragma unroll
        for (int kk = 0; kk < 16; kk++) {
            float4 a0 = *(const float4*)&xl[kk][tr * 8];
            float4 a1 = *(const float4*)&xl[kk][tr * 8 + 4];
            float4 b  = *(const float4*)&wl[kk][tc * 4];
            float av[8] = {a0.x, a0.y, a0.z, a0.w, a1.x, a1.y, a1.z, a1.w};
            float bv[4] = {b.x, b.y, b.z, b.w};
            #pragma unroll
            for (int i = 0; i < 8; i++)
                #pragma unroll
                for (int u = 0; u < 4; u++)
                    acc[i][u] += av[i] * bv[u];
        }
        __syncthreads();
    }
    #pragma unroll
    for (int i = 0; i < 8; i++) {
        int row = m0 + tr * 8 + i;
        if (row < N_NODES) {
            float dr = dis[row];
            __half2* o2 = (__half2*)&hs1[(size_t)row * H1 + tc * 4];
            o2[0] = __floats2half2_rn(acc[i][0] * dr, acc[i][1] * dr);
            o2[1] = __floats2half2_rn(acc[i][2] * dr, acc[i][3] * dr);
        }
    }
}

// ---------------- agg1: hr = relu(di * (sum hs1[s] + hs1[w]) + b1) ----------------

__global__ __launch_bounds__(256) void k_agg1(const __half* __restrict__ hs1,
                                              const float* __restrict__ dis,
                                              const int* __restrict__ csr,
                                              const int* __restrict__ offsets,
                                              const int* __restrict__ ecnt,
                                              const float* __restrict__ b1,
                                              float* __restrict__ hr) {
    int w = (blockIdx.x * 256 + threadIdx.x) >> 6;
    if (w >= N_NODES) return;
    int lane = threadIdx.x & 63;
    int j = lane * 2;
    const __half2* __restrict__ h = (const __half2*)hs1;
    float di = dis[w];
    int start = offsets[w];
    int cnt = ecnt[w];
    float2 selfv = __half22float2(h[(size_t)w * 64 + lane]);
    float sx = selfv.x;
    float sy = selfv.y;
    for (int k = 0; k < cnt; k += 8) {
        int s[8]; __half2 v[8];
        #pragma unroll
        for (int u = 0; u < 8; u++) {
            int kk = k + u;
            s[u] = csr[start + (kk < cnt ? kk : cnt - 1)];
        }
        #pragma unroll
        for (int u = 0; u < 8; u++)
            v[u] = h[(size_t)s[u] * 64 + lane];
        #pragma unroll
        for (int u = 0; u < 8; u++) {
            float2 f = __half22float2(v[u]);
            bool ok = (k + u < cnt);
            sx += ok ? f.x : 0.f;
            sy += ok ? f.y : 0.f;
        }
    }
    float2 bb = *(const float2*)&b1[j];
    float2 o = make_float2(fmaxf(bb.x + di * sx, 0.f),
                           fmaxf(bb.y + di * sy, 0.f));
    *(float2*)&hr[(size_t)w * H1 + j] = o;
}

// ---------------- GEMM2: hs2 = fp16(dis * (hr @ W2)) ----------------

__global__ __launch_bounds__(256) void k_gemm2(const float* __restrict__ hr,
                                               const float* __restrict__ W2,
                                               const float* __restrict__ dis,
                                               __half* __restrict__ hs2) {
    __shared__ float hl[32][128];
    __shared__ float wl[128][64];
    int t = threadIdx.x;
    int m0 = blockIdx.x * 32;
    #pragma unroll
    for (int j = 0; j < 8; j++) {
        int i4 = t + j * 256;
        int r = i4 >> 4, c4 = i4 & 15;
        *(float4*)&wl[r][c4 * 4] = *(const float4*)&W2[(size_t)r * H2 + c4 * 4];
    }
    #pragma unroll
    for (int j = 0; j < 4; j++) {
        int i4 = t + j * 256;
        int r = i4 >> 5, c4 = i4 & 31;
        *(float4*)&hl[r][c4 * 4] = *(const float4*)&hr[(size_t)(m0 + r) * H1 + c4 * 4];
    }
    __syncthreads();
    int c = t & 63, rg = t >> 6;
    float acc[8] = {};
    for (int k = 0; k < H1; k++) {
        float wv = wl[k][c];
        #pragma unroll
        for (int i = 0; i < 8; i++) acc[i] += hl[rg * 8 + i][k] * wv;
    }
    #pragma unroll
    for (int i = 0; i < 8; i++) {
        int row = m0 + rg * 8 + i;
        hs2[(size_t)row * H2 + c] = __float2half_rn(dis[row] * acc[i]);
    }
}

// ---------------- agg2: out = b2 + di * (sum hs2[s] + hs2[w]) ----------------

__global__ __launch_bounds__(256) void k_agg2(const __half* __restrict__ hs2,
                                              const float* __restrict__ dis,
                                              const int* __restrict__ csr,
                                              const int* __restrict__ offsets,
                                              const int* __restrict__ ecnt,
                                              const float* __restrict__ b2,
                                              float* __restrict__ out) {
    int w = (blockIdx.x * 256 + threadIdx.x) >> 6;
    if (w >= N_NODES) return;
    int lane = threadIdx.x & 63;
    float di = dis[w];
    int start = offsets[w];
    int cnt = ecnt[w];
    float acc = __half2float(hs2[(size_t)w * H2 + lane]);
    for (int k = 0; k < cnt; k += 8) {
        int s[8]; __half v[8];
        #pragma unroll
        for (int u = 0; u < 8; u++) {
            int kk = k + u;
            s[u] = csr[start + (kk < cnt ? kk : cnt - 1)];
        }
        #pragma unroll
        for (int u = 0; u < 8; u++)
            v[u] = hs2[(size_t)s[u] * H2 + lane];
        #pragma unroll
        for (int u = 0; u < 8; u++) {
            float f = __half2float(v[u]);
            acc += (k + u < cnt) ? f : 0.f;
        }
    }
    out[(size_t)w * H2 + lane] = b2[lane] + di * acc;
}

// ---------------- launch ----------------

extern "C" void kernel_launch(void* const* d_in, const int* in_sizes, int n_in,
                              void* d_out, int out_size, void* d_ws, size_t ws_size,
                              hipStream_t stream) {
    const float* x  = (const float*)d_in[0];
    const float* W1 = (const float*)d_in[1];
    const float* b1 = (const float*)d_in[2];
    const float* W2 = (const float*)d_in[3];
    const float* b2 = (const float*)d_in[4];
    const int*   ei = (const int*)d_in[5];
    const int* src = ei;
    const int* dst = ei + N_EDGES;
    float* out = (float*)d_out;

    char* ws = (char*)d_ws;
    float* dis        = (float*)ws; ws += (size_t)N_NODES * 4;
    int*   offsets    = (int*)ws;   ws += (size_t)N_NODES * 4;
    int*   ecnt       = (int*)ws;   ws += (size_t)N_NODES * 4;
    int*   bucketBase = (int*)ws;   ws += 1024 * 4;
    int*   hist       = (int*)ws;   ws += (size_t)NB_BIN * HIST_W * 4;
    int*   csr        = (int*)ws;   ws += (size_t)N_EDGES * 4;
    __half* hs1       = (__half*)ws; ws += (size_t)N_NODES * H1 * 2;
    float* hr         = (float*)ws; ws += (size_t)N_NODES * H1 * 4;
    int*   binned     = (int*)hr;   // dead before agg1 writes hr
    __half* hs2       = hs1;        // hs1 dead after agg1

    k_hist    <<<NB_BIN, 256, 0, stream>>>(dst, hist);
    k_scan_off<<<1, 1024, 0, stream>>>(hist, bucketBase);
    k_bin     <<<NB_BIN, 256, 0, stream>>>(src, dst, hist, bucketBase, binned);
    k_build   <<<NBKT, 256, 0, stream>>>(binned, bucketBase, csr, offsets, ecnt, dis);

    k_gemm1<<<(N_NODES + 63) / 64, 256, 0, stream>>>(x, W1, dis, hs1);
    k_agg1<<<(N_NODES + 3) / 4, 256, 0, stream>>>(hs1, dis, csr, offsets, ecnt, b1, hr);
    k_gemm2<<<N_NODES / 32, 256, 0, stream>>>(hr, W2, dis, hs2);
    k_agg2<<<(N_NODES + 3) / 4, 256, 0, stream>>>(hs2, dis, csr, offsets, ecnt, b2, out);
}

// Round 6
// 634.568 us; speedup vs baseline: 2.1417x; 1.0864x over previous
//
#include <hip/hip_runtime.h>
#include <hip/hip_fp16.h>
#include <math.h>

#define N_NODES 100000
#define N_EDGES 3200000
#define F_IN    384
#define H1      128
#define H2      64

#define NBKT    782          // ceil(N_NODES / 128)
#define HIST_W  800          // padded bucket-row width
#define NB_BIN  256          // binning blocks
#define EPB     (N_EDGES / NB_BIN)   // 12500 edges per bin block

typedef _Float16 f16x8 __attribute__((ext_vector_type(8)));
typedef float    f32x4 __attribute__((ext_vector_type(4)));

// ---------------- phase A1: per-block bucket histograms ----------------

__global__ __launch_bounds__(256) void k_hist(const int* __restrict__ dst,
                                              int* __restrict__ hist) {
    __shared__ int h[HIST_W];
    int b = blockIdx.x, t = threadIdx.x;
    for (int i = t; i < HIST_W; i += 256) h[i] = 0;
    __syncthreads();
    int e0 = b * EPB, e1 = e0 + EPB;
    for (int e = e0 + t; e < e1; e += 256)
        atomicAdd(&h[dst[e] >> 7], 1);
    __syncthreads();
    for (int i = t; i < HIST_W; i += 256) hist[b * HIST_W + i] = h[i];
}

// ---------------- phase A2: bucket bases + per-(block,bucket) offsets ----------------

__global__ __launch_bounds__(1024) void k_scan_off(int* __restrict__ hist,
                                                   int* __restrict__ bucketBase) {
    __shared__ int s[1024];
    int t = threadIdx.x;
    int run = 0;
    if (t < HIST_W) {
        #pragma unroll 8
        for (int b = 0; b < NB_BIN; b++) {
            int v = hist[b * HIST_W + t];
            hist[b * HIST_W + t] = run;   // prefix over blocks, within bucket
            run += v;
        }
    }
    int tot = (t < NBKT) ? run : 0;
    s[t] = tot; __syncthreads();
    for (int off = 1; off < 1024; off <<= 1) {
        int x = (t >= off) ? s[t - off] : 0;
        __syncthreads();
        s[t] += x;
        __syncthreads();
    }
    if (t <= NBKT) bucketBase[t] = s[t] - tot;   // exclusive over buckets
}

// ---------------- phase A3: scatter packed edges into bucket order ----------------

__global__ __launch_bounds__(256) void k_bin(const int* __restrict__ src,
                                             const int* __restrict__ dst,
                                             const int* __restrict__ hist,
                                             const int* __restrict__ bucketBase,
                                             int* __restrict__ binned) {
    __shared__ int lcur[HIST_W];
    int b = blockIdx.x, t = threadIdx.x;
    for (int i = t; i < HIST_W; i += 256)
        lcur[i] = ((i < NBKT) ? bucketBase[i] : 0) + hist[b * HIST_W + i];
    __syncthreads();
    int e0 = b * EPB, e1 = e0 + EPB;
    for (int e = e0 + t; e < e1; e += 256) {
        int d = dst[e];
        int p = atomicAdd(&lcur[d >> 7], 1);
        binned[p] = ((d & 127) << 17) | src[e];   // src < 2^17
    }
}

// ---------------- phase B: per-bucket deg/dis/offsets/csr (all in LDS) ----------------

__global__ __launch_bounds__(256) void k_build(const int* __restrict__ binned,
                                               const int* __restrict__ bucketBase,
                                               int* __restrict__ csr,
                                               int* __restrict__ offsets,
                                               int* __restrict__ ecnt,
                                               float* __restrict__ dis) {
    __shared__ int ldeg[128], spre[128], lcur[128];
    int bkt = blockIdx.x, t = threadIdx.x;
    int e0 = bucketBase[bkt], e1 = bucketBase[bkt + 1];
    if (t < 128) ldeg[t] = 0;
    __syncthreads();
    for (int e = e0 + t; e < e1; e += 256)
        atomicAdd(&ldeg[binned[e] >> 17], 1);
    __syncthreads();
    int v = (t < 128) ? ldeg[t] : 0;
    if (t < 128) spre[t] = v;
    __syncthreads();
    for (int off = 1; off < 128; off <<= 1) {
        int x = (t < 128 && t >= off) ? spre[t - off] : 0;
        __syncthreads();
        if (t < 128) spre[t] += x;
        __syncthreads();
    }
    if (t < 128) {
        int node = bkt * 128 + t;
        if (node < N_NODES) {
            int base = e0 + spre[t] - v;   // exclusive prefix within bucket
            offsets[node] = base;
            ecnt[node]    = v;             // neighbors excluding self-loop
            dis[node]     = rsqrtf((float)(v + 1));
            lcur[t]       = base;
        }
    }
    __syncthreads();
    for (int e = e0 + t; e < e1; e += 256) {
        int p = binned[e];
        int pos = atomicAdd(&lcur[p >> 17], 1);
        csr[pos] = p & 0x1FFFF;
    }
}

// ---------------- W1 -> fp16 transposed [H1][F_IN] ----------------

__global__ __launch_bounds__(256) void k_w1t(const float* __restrict__ W1,
                                             __half* __restrict__ w1t) {
    int id = blockIdx.x * 256 + threadIdx.x;   // over H1*F_IN
    int c = id / F_IN, k = id % F_IN;
    w1t[id] = __float2half_rn(W1[(size_t)k * H1 + c]);
}

// ---------------- GEMM1 (MFMA): hs1 = fp16(dis * (x @ W1)) ----------------
// 64x128 tile, BK=64, 4 waves x (16 rows x 128 cols) each.

__global__ __launch_bounds__(256) void k_gemm1(const float* __restrict__ x,
                                               const __half* __restrict__ w1t,
                                               const float* __restrict__ dis,
                                               __half* __restrict__ hs1) {
    __shared__ f16x8 xl[512];    // 64 rows x 64 k fp16, XOR-swizzled 16B slots
    __shared__ f16x8 wt[1024];   // 128 cols x 64 k fp16, XOR-swizzled
    int t = threadIdx.x;
    int m0 = blockIdx.x * 64;
    int wv = t >> 6, l = t & 63;
    int lrow = l & 15, kg = l >> 4;
    f32x4 acc[8];
    #pragma unroll
    for (int nb = 0; nb < 8; nb++) acc[nb] = (f32x4){0.f, 0.f, 0.f, 0.f};

    char* xb = (char*)xl;
    char* wb = (char*)wt;

    for (int k0 = 0; k0 < F_IN; k0 += 64) {
        #pragma unroll
        for (int j = 0; j < 2; j++) {            // stage x tile (fp32 -> fp16)
            int s = t + j * 256;
            int r = s >> 3, kc = (s & 7) * 8;
            int rg = m0 + r; if (rg >= N_NODES) rg = N_NODES - 1;
            const float* px = &x[(size_t)rg * F_IN + k0 + kc];
            float4 p0 = *(const float4*)px;
            float4 p1 = *(const float4*)(px + 4);
            f16x8 h;
            h[0] = (_Float16)p0.x; h[1] = (_Float16)p0.y;
            h[2] = (_Float16)p0.z; h[3] = (_Float16)p0.w;
            h[4] = (_Float16)p1.x; h[5] = (_Float16)p1.y;
            h[6] = (_Float16)p1.z; h[7] = (_Float16)p1.w;
            *(f16x8*)(xb + ((r * 128 + kc * 2) ^ ((r & 7) << 4))) = h;
        }
        #pragma unroll
        for (int j = 0; j < 4; j++) {            // stage W1^T slab (already fp16)
            int s = t + j * 256;
            int c = s >> 3, kc = (s & 7) * 8;
            f16x8 h = *(const f16x8*)&w1t[(size_t)c * F_IN + k0 + kc];
            *(f16x8*)(wb + ((c * 128 + kc * 2) ^ ((c & 7) << 4))) = h;
        }
        __syncthreads();
        #pragma unroll
        for (int ks = 0; ks < 2; ks++) {
            int r = wv * 16 + lrow;
            int kb = (ks * 32 + kg * 8) * 2;
            f16x8 a = *(const f16x8*)(xb + ((r * 128 + kb) ^ ((r & 7) << 4)));
            #pragma unroll
            for (int nb = 0; nb < 8; nb++) {
                int c = nb * 16 + lrow;
                f16x8 b = *(const f16x8*)(wb + ((c * 128 + kb) ^ ((c & 7) << 4)));
                acc[nb] = __builtin_amdgcn_mfma_f32_16x16x32_f16(a, b, acc[nb], 0, 0, 0);
            }
        }
        __syncthreads();
    }
    // D layout: col = lane&15, row = (lane>>4)*4 + reg
    int rbase = m0 + wv * 16 + kg * 4;
    #pragma unroll
    for (int reg = 0; reg < 4; reg++) {
        int row = rbase + reg;
        if (row < N_NODES) {
            float dr = dis[row];
            #pragma unroll
            for (int nb = 0; nb < 8; nb++)
                hs1[(size_t)row * H1 + nb * 16 + lrow] = __float2half_rn(acc[nb][reg] * dr);
        }
    }
}

// ---------------- agg1: hr = relu(di * (sum hs1[s] + hs1[w]) + b1) ----------------

__global__ __launch_bounds__(256) void k_agg1(const __half* __restrict__ hs1,
                                              const float* __restrict__ dis,
                                              const int* __restrict__ csr,
                                              const int* __restrict__ offsets,
                                              const int* __restrict__ ecnt,
                                              const float* __restrict__ b1,
                                              float* __restrict__ hr) {
    int w = (blockIdx.x * 256 + threadIdx.x) >> 6;
    if (w >= N_NODES) return;
    int lane = threadIdx.x & 63;
    int j = lane * 2;
    const __half2* __restrict__ h = (const __half2*)hs1;
    float di = dis[w];
    int start = offsets[w];
    int cnt = ecnt[w];
    float2 selfv = __half22float2(h[(size_t)w * 64 + lane]);
    float sx = selfv.x;
    float sy = selfv.y;
    for (int k = 0; k < cnt; k += 8) {
        int s[8]; __half2 v[8];
        #pragma unroll
        for (int u = 0; u < 8; u++) {
            int kk = k + u;
            s[u] = csr[start + (kk < cnt ? kk : cnt - 1)];
        }
        #pragma unroll
        for (int u = 0; u < 8; u++)
            v[u] = h[(size_t)s[u] * 64 + lane];
        #pragma unroll
        for (int u = 0; u < 8; u++) {
            float2 f = __half22float2(v[u]);
            bool ok = (k + u < cnt);
            sx += ok ? f.x : 0.f;
            sy += ok ? f.y : 0.f;
        }
    }
    float2 bb = *(const float2*)&b1[j];
    float2 o = make_float2(fmaxf(bb.x + di * sx, 0.f),
                           fmaxf(bb.y + di * sy, 0.f));
    *(float2*)&hr[(size_t)w * H1 + j] = o;
}

// ---------------- GEMM2: hs2 = fp16(dis * (hr @ W2)) ----------------

__global__ __launch_bounds__(256) void k_gemm2(const float* __restrict__ hr,
                                               const float* __restrict__ W2,
                                               const float* __restrict__ dis,
                                               __half* __restrict__ hs2) {
    __shared__ float hl[32][128];
    __shared__ float wl[128][64];
    int t = threadIdx.x;
    int m0 = blockIdx.x * 32;
    #pragma unroll
    for (int j = 0; j < 8; j++) {
        int i4 = t + j * 256;
        int r = i4 >> 4, c4 = i4 & 15;
        *(float4*)&wl[r][c4 * 4] = *(const float4*)&W2[(size_t)r * H2 + c4 * 4];
    }
    #pragma unroll
    for (int j = 0; j < 4; j++) {
        int i4 = t + j * 256;
        int r = i4 >> 5, c4 = i4 & 31;
        *(float4*)&hl[r][c4 * 4] = *(const float4*)&hr[(size_t)(m0 + r) * H1 + c4 * 4];
    }
    __syncthreads();
    int c = t & 63, rg = t >> 6;
    float acc[8] = {};
    for (int k = 0; k < H1; k++) {
        float wv = wl[k][c];
        #pragma unroll
        for (int i = 0; i < 8; i++) acc[i] += hl[rg * 8 + i][k] * wv;
    }
    #pragma unroll
    for (int i = 0; i < 8; i++) {
        int row = m0 + rg * 8 + i;
        hs2[(size_t)row * H2 + c] = __float2half_rn(dis[row] * acc[i]);
    }
}

// ---------------- agg2: out = b2 + di * (sum hs2[s] + hs2[w]) ----------------

__global__ __launch_bounds__(256) void k_agg2(const __half* __restrict__ hs2,
                                              const float* __restrict__ dis,
                                              const int* __restrict__ csr,
                                              const int* __restrict__ offsets,
                                              const int* __restrict__ ecnt,
                                              const float* __restrict__ b2,
                                              float* __restrict__ out) {
    int w = (blockIdx.x * 256 + threadIdx.x) >> 6;
    if (w >= N_NODES) return;
    int lane = threadIdx.x & 63;
    float di = dis[w];
    int start = offsets[w];
    int cnt = ecnt[w];
    float acc = __half2float(hs2[(size_t)w * H2 + lane]);
    for (int k = 0; k < cnt; k += 8) {
        int s[8]; __half v[8];
        #pragma unroll
        for (int u = 0; u < 8; u++) {
            int kk = k + u;
            s[u] = csr[start + (kk < cnt ? kk : cnt - 1)];
        }
        #pragma unroll
        for (int u = 0; u < 8; u++)
            v[u] = hs2[(size_t)s[u] * H2 + lane];
        #pragma unroll
        for (int u = 0; u < 8; u++) {
            float f = __half2float(v[u]);
            acc += (k + u < cnt) ? f : 0.f;
        }
    }
    out[(size_t)w * H2 + lane] = b2[lane] + di * acc;
}

// ---------------- launch ----------------

extern "C" void kernel_launch(void* const* d_in, const int* in_sizes, int n_in,
                              void* d_out, int out_size, void* d_ws, size_t ws_size,
                              hipStream_t stream) {
    const float* x  = (const float*)d_in[0];
    const float* W1 = (const float*)d_in[1];
    const float* b1 = (const float*)d_in[2];
    const float* W2 = (const float*)d_in[3];
    const float* b2 = (const float*)d_in[4];
    const int*   ei = (const int*)d_in[5];
    const int* src = ei;
    const int* dst = ei + N_EDGES;
    float* out = (float*)d_out;

    char* ws = (char*)d_ws;
    float* dis        = (float*)ws; ws += (size_t)N_NODES * 4;
    int*   offsets    = (int*)ws;   ws += (size_t)N_NODES * 4;
    int*   ecnt       = (int*)ws;   ws += (size_t)N_NODES * 4;
    int*   bucketBase = (int*)ws;   ws += 1024 * 4;
    int*   hist       = (int*)ws;   ws += (size_t)NB_BIN * HIST_W * 4;
    int*   csr        = (int*)ws;   ws += (size_t)N_EDGES * 4;
    __half* w1t       = (__half*)ws; ws += (size_t)H1 * F_IN * 2;
    __half* hs1       = (__half*)ws; ws += (size_t)N_NODES * H1 * 2;
    float* hr         = (float*)ws; ws += (size_t)N_NODES * H1 * 4;
    int*   binned     = (int*)hr;   // dead before agg1 writes hr
    __half* hs2       = hs1;        // hs1 dead after agg1

    k_w1t     <<<(H1 * F_IN) / 256, 256, 0, stream>>>(W1, w1t);
    k_hist    <<<NB_BIN, 256, 0, stream>>>(dst, hist);
    k_scan_off<<<1, 1024, 0, stream>>>(hist, bucketBase);
    k_bin     <<<NB_BIN, 256, 0, stream>>>(src, dst, hist, bucketBase, binned);
    k_build   <<<NBKT, 256, 0, stream>>>(binned, bucketBase, csr, offsets, ecnt, dis);

    k_gemm1<<<(N_NODES + 63) / 64, 256, 0, stream>>>(x, w1t, dis, hs1);
    k_agg1<<<(N_NODES + 3) / 4, 256, 0, stream>>>(hs1, dis, csr, offsets, ecnt, b1, hr);
    k_gemm2<<<N_NODES / 32, 256, 0, stream>>>(hr, W2, dis, hs2);
    k_agg2<<<(N_NODES + 3) / 4, 256, 0, stream>>>(hs2, dis, csr, offsets, ecnt, b2, out);
}

// Round 7
// 582.770 us; speedup vs baseline: 2.3320x; 1.0889x over previous
//
#include <hip/hip_runtime.h>
#include <hip/hip_fp16.h>
#include <math.h>

#define N_NODES 100000
#define N_EDGES 3200000
#define F_IN    384
#define H1      128
#define H2      64

#define NBKT    782          // ceil(N_NODES / 128)
#define HIST_W  800          // padded bucket-row width
#define NB_BIN  256          // binning blocks
#define EPB     (N_EDGES / NB_BIN)   // 12500 edges per bin block

typedef _Float16 f16x8 __attribute__((ext_vector_type(8)));
typedef float    f32x4 __attribute__((ext_vector_type(4)));

// ---------------- phase A1: per-block bucket histograms ----------------

__global__ __launch_bounds__(256) void k_hist(const int* __restrict__ dst,
                                              int* __restrict__ hist) {
    __shared__ int h[HIST_W];
    int b = blockIdx.x, t = threadIdx.x;
    for (int i = t; i < HIST_W; i += 256) h[i] = 0;
    __syncthreads();
    int e0 = b * EPB, e1 = e0 + EPB;
    for (int e = e0 + t; e < e1; e += 256)
        atomicAdd(&h[dst[e] >> 7], 1);
    __syncthreads();
    for (int i = t; i < HIST_W; i += 256) hist[b * HIST_W + i] = h[i];
}

// ---------------- phase A2: bucket bases + per-(block,bucket) offsets ----------------

__global__ __launch_bounds__(1024) void k_scan_off(int* __restrict__ hist,
                                                   int* __restrict__ bucketBase) {
    __shared__ int s[1024];
    int t = threadIdx.x;
    int run = 0;
    if (t < HIST_W) {
        #pragma unroll 8
        for (int b = 0; b < NB_BIN; b++) {
            int v = hist[b * HIST_W + t];
            hist[b * HIST_W + t] = run;   // prefix over blocks, within bucket
            run += v;
        }
    }
    int tot = (t < NBKT) ? run : 0;
    s[t] = tot; __syncthreads();
    for (int off = 1; off < 1024; off <<= 1) {
        int x = (t >= off) ? s[t - off] : 0;
        __syncthreads();
        s[t] += x;
        __syncthreads();
    }
    if (t <= NBKT) bucketBase[t] = s[t] - tot;   // exclusive over buckets
}

// ---------------- phase A3: scatter packed edges into bucket order ----------------

__global__ __launch_bounds__(256) void k_bin(const int* __restrict__ src,
                                             const int* __restrict__ dst,
                                             const int* __restrict__ hist,
                                             const int* __restrict__ bucketBase,
                                             int* __restrict__ binned) {
    __shared__ int lcur[HIST_W];
    int b = blockIdx.x, t = threadIdx.x;
    for (int i = t; i < HIST_W; i += 256)
        lcur[i] = ((i < NBKT) ? bucketBase[i] : 0) + hist[b * HIST_W + i];
    __syncthreads();
    int e0 = b * EPB, e1 = e0 + EPB;
    for (int e = e0 + t; e < e1; e += 256) {
        int d = dst[e];
        int p = atomicAdd(&lcur[d >> 7], 1);
        binned[p] = ((d & 127) << 17) | src[e];   // src < 2^17
    }
}

// ---------------- phase B: per-bucket deg/dis/offsets/csr (all in LDS) ----------------

__global__ __launch_bounds__(256) void k_build(const int* __restrict__ binned,
                                               const int* __restrict__ bucketBase,
                                               int* __restrict__ csr,
                                               int* __restrict__ offsets,
                                               int* __restrict__ ecnt,
                                               float* __restrict__ dis) {
    __shared__ int ldeg[128], spre[128], lcur[128];
    int bkt = blockIdx.x, t = threadIdx.x;
    int e0 = bucketBase[bkt], e1 = bucketBase[bkt + 1];
    if (t < 128) ldeg[t] = 0;
    __syncthreads();
    for (int e = e0 + t; e < e1; e += 256)
        atomicAdd(&ldeg[binned[e] >> 17], 1);
    __syncthreads();
    int v = (t < 128) ? ldeg[t] : 0;
    if (t < 128) spre[t] = v;
    __syncthreads();
    for (int off = 1; off < 128; off <<= 1) {
        int x = (t < 128 && t >= off) ? spre[t - off] : 0;
        __syncthreads();
        if (t < 128) spre[t] += x;
        __syncthreads();
    }
    if (t < 128) {
        int node = bkt * 128 + t;
        if (node < N_NODES) {
            int base = e0 + spre[t] - v;   // exclusive prefix within bucket
            offsets[node] = base;
            ecnt[node]    = v;             // neighbors excluding self-loop
            dis[node]     = rsqrtf((float)(v + 1));
            lcur[t]       = base;
        }
    }
    __syncthreads();
    for (int e = e0 + t; e < e1; e += 256) {
        int p = binned[e];
        int pos = atomicAdd(&lcur[p >> 17], 1);
        csr[pos] = p & 0x1FFFF;
    }
}

// ---------------- weight transposes to fp16 ----------------

__global__ __launch_bounds__(256) void k_w1t(const float* __restrict__ W1,
                                             __half* __restrict__ w1t) {
    int id = blockIdx.x * 256 + threadIdx.x;   // over H1*F_IN
    int c = id / F_IN, k = id % F_IN;
    w1t[id] = __float2half_rn(W1[(size_t)k * H1 + c]);
}

__global__ __launch_bounds__(256) void k_w2t(const float* __restrict__ W2,
                                             __half* __restrict__ w2t) {
    int id = blockIdx.x * 256 + threadIdx.x;   // over H2*H1
    int c = id / H1, k = id % H1;
    w2t[id] = __float2half_rn(W2[(size_t)k * H2 + c]);
}

// ---------------- GEMM1 (MFMA): hs1 = fp16(dis * (x @ W1)) ----------------
// 64x128 tile, BK=64, 4 waves x (16 rows x 128 cols) each.

__global__ __launch_bounds__(256) void k_gemm1(const float* __restrict__ x,
                                               const __half* __restrict__ w1t,
                                               const float* __restrict__ dis,
                                               __half* __restrict__ hs1) {
    __shared__ f16x8 xl[512];    // 64 rows x 64 k fp16, XOR-swizzled 16B slots
    __shared__ f16x8 wt[1024];   // 128 cols x 64 k fp16, XOR-swizzled
    int t = threadIdx.x;
    int m0 = blockIdx.x * 64;
    int wv = t >> 6, l = t & 63;
    int lrow = l & 15, kg = l >> 4;
    f32x4 acc[8];
    #pragma unroll
    for (int nb = 0; nb < 8; nb++) acc[nb] = (f32x4){0.f, 0.f, 0.f, 0.f};

    char* xb = (char*)xl;
    char* wb = (char*)wt;

    for (int k0 = 0; k0 < F_IN; k0 += 64) {
        #pragma unroll
        for (int j = 0; j < 2; j++) {            // stage x tile (fp32 -> fp16)
            int s = t + j * 256;
            int r = s >> 3, kc = (s & 7) * 8;
            int rg = m0 + r; if (rg >= N_NODES) rg = N_NODES - 1;
            const float* px = &x[(size_t)rg * F_IN + k0 + kc];
            float4 p0 = *(const float4*)px;
            float4 p1 = *(const float4*)(px + 4);
            f16x8 h;
            h[0] = (_Float16)p0.x; h[1] = (_Float16)p0.y;
            h[2] = (_Float16)p0.z; h[3] = (_Float16)p0.w;
            h[4] = (_Float16)p1.x; h[5] = (_Float16)p1.y;
            h[6] = (_Float16)p1.z; h[7] = (_Float16)p1.w;
            *(f16x8*)(xb + ((r * 128 + kc * 2) ^ ((r & 7) << 4))) = h;
        }
        #pragma unroll
        for (int j = 0; j < 4; j++) {            // stage W1^T slab (already fp16)
            int s = t + j * 256;
            int c = s >> 3, kc = (s & 7) * 8;
            f16x8 h = *(const f16x8*)&w1t[(size_t)c * F_IN + k0 + kc];
            *(f16x8*)(wb + ((c * 128 + kc * 2) ^ ((c & 7) << 4))) = h;
        }
        __syncthreads();
        #pragma unroll
        for (int ks = 0; ks < 2; ks++) {
            int r = wv * 16 + lrow;
            int kb = (ks * 32 + kg * 8) * 2;
            f16x8 a = *(const f16x8*)(xb + ((r * 128 + kb) ^ ((r & 7) << 4)));
            #pragma unroll
            for (int nb = 0; nb < 8; nb++) {
                int c = nb * 16 + lrow;
                f16x8 b = *(const f16x8*)(wb + ((c * 128 + kb) ^ ((c & 7) << 4)));
                acc[nb] = __builtin_amdgcn_mfma_f32_16x16x32_f16(a, b, acc[nb], 0, 0, 0);
            }
        }
        __syncthreads();
    }
    // D layout: col = lane&15, row = (lane>>4)*4 + reg
    int rbase = m0 + wv * 16 + kg * 4;
    #pragma unroll
    for (int reg = 0; reg < 4; reg++) {
        int row = rbase + reg;
        if (row < N_NODES) {
            float dr = dis[row];
            #pragma unroll
            for (int nb = 0; nb < 8; nb++)
                hs1[(size_t)row * H1 + nb * 16 + lrow] = __float2half_rn(acc[nb][reg] * dr);
        }
    }
}

// ---------------- agg1: hr = relu(di * (sum hs1[s] + hs1[w]) + b1) ----------------
// 2 nodes per wave; half-wave of 32 lanes x 4 features (8B loads).

__global__ __launch_bounds__(256) void k_agg1(const __half* __restrict__ hs1,
                                              const float* __restrict__ dis,
                                              const int* __restrict__ csr,
                                              const int* __restrict__ offsets,
                                              const int* __restrict__ ecnt,
                                              const float* __restrict__ b1,
                                              float* __restrict__ hr) {
    int t = threadIdx.x;
    int w = blockIdx.x * 8 + ((t >> 6) << 1) + ((t & 63) >> 5);  // node
    int fl = t & 31;                                             // feature group
    int f4 = fl << 2;
    float di = dis[w];
    int start = offsets[w];
    int cnt = ecnt[w];
    uint2 selfr = *(const uint2*)(hs1 + ((unsigned)w << 7) + f4);
    float2 s0 = __half22float2(*(__half2*)&selfr.x);
    float2 s1 = __half22float2(*(__half2*)&selfr.y);
    float a0 = s0.x, a1 = s0.y, a2 = s1.x, a3 = s1.y;

    int kfull = cnt & ~7;
    for (int k = 0; k < kfull; k += 8) {
        int s[8]; uint2 r[8];
        #pragma unroll
        for (int u = 0; u < 8; u++) s[u] = csr[start + k + u];
        #pragma unroll
        for (int u = 0; u < 8; u++)
            r[u] = *(const uint2*)(hs1 + (((unsigned)s[u] << 7) | f4));
        #pragma unroll
        for (int u = 0; u < 8; u++) {
            float2 f0 = __half22float2(*(__half2*)&r[u].x);
            float2 f1 = __half22float2(*(__half2*)&r[u].y);
            a0 += f0.x; a1 += f0.y; a2 += f1.x; a3 += f1.y;
        }
    }
    for (int k = kfull; k < cnt; k++) {
        int s = csr[start + k];
        uint2 rr = *(const uint2*)(hs1 + (((unsigned)s << 7) | f4));
        float2 f0 = __half22float2(*(__half2*)&rr.x);
        float2 f1 = __half22float2(*(__half2*)&rr.y);
        a0 += f0.x; a1 += f0.y; a2 += f1.x; a3 += f1.y;
    }
    float4 bb = *(const float4*)&b1[f4];
    float4 o = make_float4(fmaxf(bb.x + di * a0, 0.f),
                           fmaxf(bb.y + di * a1, 0.f),
                           fmaxf(bb.z + di * a2, 0.f),
                           fmaxf(bb.w + di * a3, 0.f));
    *(float4*)&hr[((size_t)w << 7) + f4] = o;
}

// ---------------- GEMM2 (MFMA): hs2 = fp16(dis * (hr @ W2)) ----------------
// 64x64 tile, BK=128 (whole H1), 4 waves x (16 rows x 64 cols).

__global__ __launch_bounds__(256) void k_gemm2(const float* __restrict__ hr,
                                               const __half* __restrict__ w2t,
                                               const float* __restrict__ dis,
                                               __half* __restrict__ hs2) {
    __shared__ f16x8 al[1024];   // 64 rows x 128 k fp16, XOR-swizzled
    __shared__ f16x8 bl[1024];   // 64 cols x 128 k fp16, XOR-swizzled
    int t = threadIdx.x;
    int m0 = blockIdx.x * 64;
    int wv = t >> 6, l = t & 63;
    int lrow = l & 15, kg = l >> 4;
    char* ab = (char*)al;
    char* bb = (char*)bl;

    #pragma unroll
    for (int j = 0; j < 4; j++) {            // stage hr tile (fp32 -> fp16)
        int s = t + j * 256;
        int r = s >> 4, kc = (s & 15) * 8;
        int rg = m0 + r; if (rg >= N_NODES) rg = N_NODES - 1;
        const float* ph = &hr[(size_t)rg * H1 + kc];
        float4 p0 = *(const float4*)ph;
        float4 p1 = *(const float4*)(ph + 4);
        f16x8 h;
        h[0] = (_Float16)p0.x; h[1] = (_Float16)p0.y;
        h[2] = (_Float16)p0.z; h[3] = (_Float16)p0.w;
        h[4] = (_Float16)p1.x; h[5] = (_Float16)p1.y;
        h[6] = (_Float16)p1.z; h[7] = (_Float16)p1.w;
        *(f16x8*)(ab + ((r * 256 + kc * 2) ^ ((r & 7) << 4))) = h;
    }
    #pragma unroll
    for (int j = 0; j < 4; j++) {            // stage W2^T (fp16)
        int s = t + j * 256;
        int c = s >> 4, kc = (s & 15) * 8;
        f16x8 h = *(const f16x8*)&w2t[(size_t)c * H1 + kc];
        *(f16x8*)(bb + ((c * 256 + kc * 2) ^ ((c & 7) << 4))) = h;
    }
    __syncthreads();

    f32x4 acc[4];
    #pragma unroll
    for (int nb = 0; nb < 4; nb++) acc[nb] = (f32x4){0.f, 0.f, 0.f, 0.f};
    #pragma unroll
    for (int ks = 0; ks < 4; ks++) {
        int r = wv * 16 + lrow;
        int kb = (ks * 32 + kg * 8) * 2;
        f16x8 a = *(const f16x8*)(ab + ((r * 256 + kb) ^ ((r & 7) << 4)));
        #pragma unroll
        for (int nb = 0; nb < 4; nb++) {
            int c = nb * 16 + lrow;
            f16x8 b = *(const f16x8*)(bb + ((c * 256 + kb) ^ ((c & 7) << 4)));
            acc[nb] = __builtin_amdgcn_mfma_f32_16x16x32_f16(a, b, acc[nb], 0, 0, 0);
        }
    }
    int rbase = m0 + wv * 16 + kg * 4;
    #pragma unroll
    for (int reg = 0; reg < 4; reg++) {
        int row = rbase + reg;
        if (row < N_NODES) {
            float dr = dis[row];
            #pragma unroll
            for (int nb = 0; nb < 4; nb++)
                hs2[(size_t)row * H2 + nb * 16 + lrow] = __float2half_rn(acc[nb][reg] * dr);
        }
    }
}

// ---------------- agg2: out = b2 + di * (sum hs2[s] + hs2[w]) ----------------
// 4 nodes per wave; 16 lanes x 4 features (8B loads).

__global__ __launch_bounds__(256) void k_agg2(const __half* __restrict__ hs2,
                                              const float* __restrict__ dis,
                                              const int* __restrict__ csr,
                                              const int* __restrict__ offsets,
                                              const int* __restrict__ ecnt,
                                              const float* __restrict__ b2,
                                              float* __restrict__ out) {
    int t = threadIdx.x;
    int w = blockIdx.x * 16 + ((t >> 6) << 2) + ((t & 63) >> 4);
    int fl = t & 15;
    int f4 = fl << 2;
    float di = dis[w];
    int start = offsets[w];
    int cnt = ecnt[w];
    uint2 selfr = *(const uint2*)(hs2 + ((unsigned)w << 6) + f4);
    float2 s0 = __half22float2(*(__half2*)&selfr.x);
    float2 s1 = __half22float2(*(__half2*)&selfr.y);
    float a0 = s0.x, a1 = s0.y, a2 = s1.x, a3 = s1.y;

    int kfull = cnt & ~7;
    for (int k = 0; k < kfull; k += 8) {
        int s[8]; uint2 r[8];
        #pragma unroll
        for (int u = 0; u < 8; u++) s[u] = csr[start + k + u];
        #pragma unroll
        for (int u = 0; u < 8; u++)
            r[u] = *(const uint2*)(hs2 + (((unsigned)s[u] << 6) | f4));
        #pragma unroll
        for (int u = 0; u < 8; u++) {
            float2 f0 = __half22float2(*(__half2*)&r[u].x);
            float2 f1 = __half22float2(*(__half2*)&r[u].y);
            a0 += f0.x; a1 += f0.y; a2 += f1.x; a3 += f1.y;
        }
    }
    for (int k = kfull; k < cnt; k++) {
        int s = csr[start + k];
        uint2 rr = *(const uint2*)(hs2 + (((unsigned)s << 6) | f4));
        float2 f0 = __half22float2(*(__half2*)&rr.x);
        float2 f1 = __half22float2(*(__half2*)&rr.y);
        a0 += f0.x; a1 += f0.y; a2 += f1.x; a3 += f1.y;
    }
    float4 bb = *(const float4*)&b2[f4];
    float4 o = make_float4(bb.x + di * a0, bb.y + di * a1,
                           bb.z + di * a2, bb.w + di * a3);
    *(float4*)&out[((size_t)w << 6) + f4] = o;
}

// ---------------- launch ----------------

extern "C" void kernel_launch(void* const* d_in, const int* in_sizes, int n_in,
                              void* d_out, int out_size, void* d_ws, size_t ws_size,
                              hipStream_t stream) {
    const float* x  = (const float*)d_in[0];
    const float* W1 = (const float*)d_in[1];
    const float* b1 = (const float*)d_in[2];
    const float* W2 = (const float*)d_in[3];
    const float* b2 = (const float*)d_in[4];
    const int*   ei = (const int*)d_in[5];
    const int* src = ei;
    const int* dst = ei + N_EDGES;
    float* out = (float*)d_out;

    char* ws = (char*)d_ws;
    float* dis        = (float*)ws; ws += (size_t)N_NODES * 4;
    int*   offsets    = (int*)ws;   ws += (size_t)N_NODES * 4;
    int*   ecnt       = (int*)ws;   ws += (size_t)N_NODES * 4;
    int*   bucketBase = (int*)ws;   ws += 1024 * 4;
    int*   hist       = (int*)ws;   ws += (size_t)NB_BIN * HIST_W * 4;
    int*   csr        = (int*)ws;   ws += (size_t)N_EDGES * 4;
    __half* w1t       = (__half*)ws; ws += (size_t)H1 * F_IN * 2;
    __half* w2t       = (__half*)ws; ws += (size_t)H2 * H1 * 2;
    __half* hs1       = (__half*)ws; ws += (size_t)N_NODES * H1 * 2;
    float* hr         = (float*)ws; ws += (size_t)N_NODES * H1 * 4;
    int*   binned     = (int*)hr;   // dead before agg1 writes hr
    __half* hs2       = hs1;        // hs1 dead after agg1

    k_w1t     <<<(H1 * F_IN) / 256, 256, 0, stream>>>(W1, w1t);
    k_w2t     <<<(H2 * H1) / 256, 256, 0, stream>>>(W2, w2t);
    k_hist    <<<NB_BIN, 256, 0, stream>>>(dst, hist);
    k_scan_off<<<1, 1024, 0, stream>>>(hist, bucketBase);
    k_bin     <<<NB_BIN, 256, 0, stream>>>(src, dst, hist, bucketBase, binned);
    k_build   <<<NBKT, 256, 0, stream>>>(binned, bucketBase, csr, offsets, ecnt, dis);

    k_gemm1<<<(N_NODES + 63) / 64, 256, 0, stream>>>(x, w1t, dis, hs1);
    k_agg1<<<N_NODES / 8, 256, 0, stream>>>(hs1, dis, csr, offsets, ecnt, b1, hr);
    k_gemm2<<<(N_NODES + 63) / 64, 256, 0, stream>>>(hr, w2t, dis, hs2);
    k_agg2<<<N_NODES / 16, 256, 0, stream>>>(hs2, dis, csr, offsets, ecnt, b2, out);
}